// Round 1
// baseline (916.862 us; speedup 1.0000x reference)
//
#include <hip/hip_runtime.h>

#define TT 32
#define DIN 15

__device__ __forceinline__ float sigm(float x){ return 1.f/(1.f+__expf(-x)); }
// safe tanh: never NaN on overflow
__device__ __forceinline__ float tanh_(float x){ float e=__expf(2.f*x); return 1.f - 2.f/(e+1.f); }
__device__ __forceinline__ float dot4(float4 a, float4 b, float acc){
  acc = fmaf(a.x,b.x,acc); acc = fmaf(a.y,b.y,acc);
  acc = fmaf(a.z,b.z,acc); acc = fmaf(a.w,b.w,acc); return acc;
}

// ---------------- prep: transpose Wih1 [192,15] -> [15,192] ----------------
__global__ void prep_wih1T(const float* __restrict__ wih1, float* __restrict__ wih1T){
  int i = blockIdx.x*256 + threadIdx.x;   // 0..2879
  if (i < 2880){ int k = i/192; int j = i - k*192; wih1T[i] = wih1[j*15+k]; }
}

// ---------------- fused 2-layer GRU + temporal attention ----------------
// grid 500 x 512. Each wave owns 4 consecutive sequences; lane = hidden idx.
__global__ __launch_bounds__(512, 2) void gru_fused(
    const float* __restrict__ raw,
    const float* __restrict__ wih1T,   // [15][192] (ws)
    const float* __restrict__ whh1,    // [192][64]
    const float* __restrict__ bih1, const float* __restrict__ bhh1,
    const float* __restrict__ wih2,    // [192][64]
    const float* __restrict__ whh2,    // [192][64]
    const float* __restrict__ bih2, const float* __restrict__ bhh2,
    const float* __restrict__ attnW, const float* __restrict__ attnb,
    float* __restrict__ Ai)            // [16000][64] (ws)
{
  __shared__ float wh1s[192*64];
  __shared__ float wi2s[192*64];
  __shared__ float wh2s[192*64];
  __shared__ float h1s[32*64];
  __shared__ float h2s[32*64];

  const int tid = threadIdx.x;
  // stage 3 weight matrices, chunk-XOR swizzled: chunk c of row j stored at c^(j&15)
  {
    const float4* s1=(const float4*)whh1; const float4* s2=(const float4*)wih2; const float4* s3=(const float4*)whh2;
    float4* d1=(float4*)wh1s; float4* d2=(float4*)wi2s; float4* d3=(float4*)wh2s;
    #pragma unroll
    for (int f=0; f<6; ++f){
      const int i4 = tid + f*512;          // 0..3071
      const int j = i4 >> 4, c = i4 & 15;
      const int dst = j*16 + (c ^ (j & 15));
      d1[dst]=s1[i4]; d2[dst]=s2[i4]; d3[dst]=s3[i4];
    }
  }
  const int lane = tid & 63;
  const int wave = tid >> 6;
  const int srow = wave*4;
  #pragma unroll
  for (int s=0;s<4;++s){ h1s[(srow+s)*64+lane]=0.f; h2s[(srow+s)*64+lane]=0.f; }
  __syncthreads();

  const int seq0 = blockIdx.x*32 + srow;

  const float bi1r=bih1[lane], bi1z=bih1[64+lane], bi1n=bih1[128+lane];
  const float bh1r=bhh1[lane], bh1z=bhh1[64+lane], bh1n=bhh1[128+lane];
  const float bi2r=bih2[lane], bi2z=bih2[64+lane], bi2n=bih2[128+lane];
  const float bh2r=bhh2[lane], bh2z=bhh2[64+lane], bh2n=bhh2[128+lane];
  const float awj = attnW[lane];
  const float ab  = attnb[0];

  float h1r_[4]={0,0,0,0}, h2r_[4]={0,0,0,0};
  float num[4]={0,0,0,0}, den[4]={0,0,0,0};

  const int xs = lane/15, xk = lane - xs*15;   // lanes 0..59 hold x_t for the 4 seqs

  for (int t=0; t<TT; ++t){
    float xl = 0.f;
    if (lane < 60) xl = raw[(size_t)(seq0+xs)*(TT*DIN) + t*DIN + xk];

    // ---- layer1 recurrent: gh1 = Whh1 @ h1_old (+bhh1)
    float hr[4], hz[4], hn[4];
    #pragma unroll
    for (int s=0;s<4;++s){ hr[s]=bh1r; hz[s]=bh1z; hn[s]=bh1n; }
    #pragma unroll 4
    for (int c=0;c<16;++c){
      const int cs = c ^ (lane & 15);
      const float4 wr = ((const float4*)wh1s)[ lane     *16 + cs];
      const float4 wz = ((const float4*)wh1s)[(64+lane) *16 + cs];
      const float4 wn = ((const float4*)wh1s)[(128+lane)*16 + cs];
      #pragma unroll
      for (int s=0;s<4;++s){
        const float4 h4 = ((const float4*)h1s)[(srow+s)*16 + c];
        hr[s]=dot4(h4,wr,hr[s]); hz[s]=dot4(h4,wz,hz[s]); hn[s]=dot4(h4,wn,hn[s]);
      }
    }
    // ---- layer1 input projection (+bih1)
    float xr[4], xz[4], xn[4];
    #pragma unroll
    for (int s=0;s<4;++s){ xr[s]=bi1r; xz[s]=bi1z; xn[s]=bi1n; }
    #pragma unroll 5
    for (int k=0;k<DIN;++k){
      const float wr = wih1T[k*192 + lane];
      const float wz = wih1T[k*192 + 64 + lane];
      const float wn = wih1T[k*192 + 128 + lane];
      #pragma unroll
      for (int s=0;s<4;++s){
        const float xv = __shfl(xl, s*15 + k, 64);
        xr[s]=fmaf(xv,wr,xr[s]); xz[s]=fmaf(xv,wz,xz[s]); xn[s]=fmaf(xv,wn,xn[s]);
      }
    }
    // ---- gates layer1 -> h1_new
    #pragma unroll
    for (int s=0;s<4;++s){
      const float r = sigm(xr[s]+hr[s]);
      const float z = sigm(xz[s]+hz[s]);
      const float n = tanh_(xn[s] + r*hn[s]);
      const float hv = (1.f - z)*n + z*h1r_[s];
      h1r_[s]=hv;
      h1s[(srow+s)*64 + lane] = hv;
    }
    __builtin_amdgcn_wave_barrier();  // same-wave DS ordering keeps h1 write->read safe

    // ---- layer2: xp2 = Wih2 @ h1_new, gh2 = Whh2 @ h2_old
    float r2[4], z2[4], n2[4], hr2[4], hz2[4], hn2[4];
    #pragma unroll
    for (int s=0;s<4;++s){ r2[s]=bi2r; z2[s]=bi2z; n2[s]=bi2n; hr2[s]=bh2r; hz2[s]=bh2z; hn2[s]=bh2n; }
    #pragma unroll 2
    for (int c=0;c<16;++c){
      const int cs = c ^ (lane & 15);
      const float4 ar = ((const float4*)wi2s)[ lane     *16 + cs];
      const float4 az = ((const float4*)wi2s)[(64+lane) *16 + cs];
      const float4 an = ((const float4*)wi2s)[(128+lane)*16 + cs];
      const float4 br = ((const float4*)wh2s)[ lane     *16 + cs];
      const float4 bz = ((const float4*)wh2s)[(64+lane) *16 + cs];
      const float4 bn = ((const float4*)wh2s)[(128+lane)*16 + cs];
      #pragma unroll
      for (int s=0;s<4;++s){
        const float4 g4 = ((const float4*)h1s)[(srow+s)*16 + c];
        const float4 q4 = ((const float4*)h2s)[(srow+s)*16 + c];
        r2[s]=dot4(g4,ar,r2[s]);  z2[s]=dot4(g4,az,z2[s]);  n2[s]=dot4(g4,an,n2[s]);
        hr2[s]=dot4(q4,br,hr2[s]); hz2[s]=dot4(q4,bz,hz2[s]); hn2[s]=dot4(q4,bn,hn2[s]);
      }
    }
    // ---- gates layer2 -> h2_new, online temporal-attention accumulate
    #pragma unroll
    for (int s=0;s<4;++s){
      const float r = sigm(r2[s]+hr2[s]);
      const float z = sigm(z2[s]+hz2[s]);
      const float n = tanh_(n2[s] + r*hn2[s]);
      const float hv = (1.f - z)*n + z*h2r_[s];
      h2r_[s]=hv;
      h2s[(srow+s)*64 + lane] = hv;
      float v = hv*awj;
      #pragma unroll
      for (int off=32; off>0; off>>=1) v += __shfl_xor(v, off, 64);
      const float sc = tanh_(v + ab);       // score in [-1,1] -> exp safe, no max-tracking
      const float e  = __expf(sc);
      den[s]+=e; num[s]=fmaf(e,hv,num[s]);
    }
    __builtin_amdgcn_wave_barrier();
  }
  #pragma unroll
  for (int s=0;s<4;++s) Ai[(size_t)(seq0+s)*64 + lane] = num[s]/den[s];
}

// ---------------- GAT projections: sq -> (s_q,s_k), proj ----------------
// grid 4000 x 256, one row per wave
__global__ __launch_bounds__(256) void gat_proj(
    const float* __restrict__ Ai,
    const float* __restrict__ Ww, const float* __restrict__ Wb,
    const float* __restrict__ u,
    const float* __restrict__ W1, const float* __restrict__ W1b,
    float* __restrict__ sqo, float* __restrict__ sko, float* __restrict__ proj)
{
  __shared__ float wws[64*64];
  __shared__ float w1s[64*64];
  __shared__ float rowb[4*64];
  const int tid = threadIdx.x;
  {
    const float4* s1=(const float4*)Ww; const float4* s2=(const float4*)W1;
    float4* d1=(float4*)wws; float4* d2=(float4*)w1s;
    #pragma unroll
    for (int f=0; f<4; ++f){
      const int i4 = tid + f*256;          // 0..1023
      const int j = i4 >> 4, c = i4 & 15;
      const int dst = j*16 + (c ^ (j & 15));
      d1[dst]=s1[i4]; d2[dst]=s2[i4];
    }
  }
  const int lane = tid & 63;
  const int wave = tid >> 6;
  const int row = blockIdx.x*4 + wave;
  const float ai = Ai[(size_t)row*64 + lane];
  rowb[wave*64+lane] = ai;
  __syncthreads();

  float sq = Wb[lane], pj = W1b[lane];
  #pragma unroll 4
  for (int c=0;c<16;++c){
    const int cs = c ^ (lane & 15);
    const float4 a4 = ((const float4*)rowb)[wave*16 + c];
    const float4 w4 = ((const float4*)wws)[lane*16 + cs];
    const float4 v4 = ((const float4*)w1s)[lane*16 + cs];
    sq = dot4(a4,w4,sq); pj = dot4(a4,v4,pj);
  }
  float aq = sq*u[lane];
  float ak = sq*u[64+lane];
  #pragma unroll
  for (int off=32; off>0; off>>=1){ aq += __shfl_xor(aq,off,64); ak += __shfl_xor(ak,off,64); }
  if (lane==0){ sqo[row]=aq; sko[row]=ak; }
  proj[(size_t)row*64+lane] = pj;
}

// ---------------- GAT aggregation: softmax over neighbors + weighted sum ----------------
// grid 1000 x 256; wave -> (4 q's, one b); lane = d
__global__ __launch_bounds__(256) void gat_agg(
    const float* __restrict__ sqo, const float* __restrict__ sko,
    const float* __restrict__ proj, float* __restrict__ out)
{
  const int tid = threadIdx.x;
  const int lane = tid & 63;
  const int w = blockIdx.x*4 + (tid>>6);   // 0..3999
  const int b = w & 31;
  const int q0 = (w >> 5) * 4;             // 0..496
  float sq[4], den[4]={0,0,0,0}, acc[4]={0,0,0,0};
  #pragma unroll
  for (int i=0;i<4;++i) sq[i] = sqo[(q0+i)*32 + b];
  for (int k=0;k<500;++k){
    const float sk = sko[k*32 + b];
    const float p  = proj[(size_t)(k*32 + b)*64 + lane];
    #pragma unroll
    for (int i=0;i<4;++i){
      float sc = sq[i] + sk;
      sc = sc > 0.f ? sc : 0.01f*sc;       // leaky_relu(0.01)
      const float e = __expf(sc);
      den[i] += e; acc[i] = fmaf(e, p, acc[i]);
    }
  }
  #pragma unroll
  for (int i=0;i<4;++i){
    const float g = acc[i]/den[i];
    out[(size_t)((q0+i)*32 + b)*64 + lane] = g > 0.f ? g : 0.f;
  }
}

extern "C" void kernel_launch(void* const* d_in, const int* in_sizes, int n_in,
                              void* d_out, int out_size, void* d_ws, size_t ws_size,
                              hipStream_t stream) {
  const float* raw   = (const float*)d_in[0];
  const float* w1ih  = (const float*)d_in[1];
  const float* w1hh  = (const float*)d_in[2];
  const float* b1ih  = (const float*)d_in[3];
  const float* b1hh  = (const float*)d_in[4];
  const float* w2ih  = (const float*)d_in[5];
  const float* w2hh  = (const float*)d_in[6];
  const float* b2ih  = (const float*)d_in[7];
  const float* b2hh  = (const float*)d_in[8];
  const float* attW  = (const float*)d_in[9];
  const float* attb  = (const float*)d_in[10];
  const float* gWw   = (const float*)d_in[11];
  const float* gWb   = (const float*)d_in[12];
  const float* gu    = (const float*)d_in[13];
  const float* gW1   = (const float*)d_in[14];
  const float* gW1b  = (const float*)d_in[15];
  float* outp = (float*)d_out;

  float* ws    = (float*)d_ws;
  float* Ai    = ws;                 // 1,024,000 floats
  float* proj  = ws + 1024000;       // 1,024,000
  float* sqo   = ws + 2048000;       // 16,000
  float* sko   = ws + 2064000;       // 16,000
  float* wih1T = ws + 2080000;       // 2,880

  prep_wih1T<<<12, 256, 0, stream>>>(w1ih, wih1T);
  gru_fused<<<500, 512, 0, stream>>>(raw, wih1T, w1hh, b1ih, b1hh,
                                     w2ih, w2hh, b2ih, b2hh, attW, attb, Ai);
  gat_proj<<<4000, 256, 0, stream>>>(Ai, gWw, gWb, gu, gW1, gW1b, sqo, sko, proj);
  gat_agg<<<1000, 256, 0, stream>>>(sqo, sko, proj, outp);
}

// Round 2
// 310.592 us; speedup vs baseline: 2.9520x; 2.9520x over previous
//
#include <hip/hip_runtime.h>

#define TT 32
#define DIN 15

typedef _Float16 f16x8 __attribute__((ext_vector_type(8)));
typedef _Float16 f16x4 __attribute__((ext_vector_type(4)));
typedef float f32x4 __attribute__((ext_vector_type(4)));

__device__ __forceinline__ float sigm(float x){ return 1.f/(1.f+__expf(-x)); }
// safe tanh: never NaN on overflow
__device__ __forceinline__ float tanh_(float x){ float e=__expf(2.f*x); return 1.f - 2.f/(e+1.f); }
__device__ __forceinline__ float dot4(float4 a, float4 b, float acc){
  acc = fmaf(a.x,b.x,acc); acc = fmaf(a.y,b.y,acc);
  acc = fmaf(a.z,b.z,acc); acc = fmaf(a.w,b.w,acc); return acc;
}

#define MFMA(a,b,c) __builtin_amdgcn_mfma_f32_16x16x32_f16(a,b,c,0,0,0)

__device__ __forceinline__ f16x8 f16x8_zero(){
  f16x8 v;
  #pragma unroll
  for (int j=0;j<8;++j) v[j]=(_Float16)0.f;
  return v;
}

// ---------------- prep: W -> f16 A-fragments ----------------
// frag chunk layout (16B units): whh1 @0, wih2 @1536, whh2 @3072 : idx=((ht*3+g3)*2+kf)*64+lane
//                                wih1 @4608 (kf=0 only, K padded 15->32): idx=(ht*3+g3)*64+lane
// element e of chunk: W[g3*64 + ht*16 + (lane&15)][kf*32 + (lane>>4)*8 + e]
__global__ void wprep(const float* __restrict__ w1ih, const float* __restrict__ w1hh,
                      const float* __restrict__ w2ih, const float* __restrict__ w2hh,
                      _Float16* __restrict__ wf){
  int id = blockIdx.x*256 + threadIdx.x;   // 0..43007
  if (id >= 43008) return;
  int e = id & 7, c = id >> 3;             // c: 0..5375
  const float* W; int Kdim, lane, kf, q;
  if (c < 4608){
    int mat = c / 1536; int r = c - mat*1536;
    lane = r & 63; kf = (r>>6)&1; q = r>>7;
    W = (mat==0)? w1hh : (mat==1)? w2ih : w2hh; Kdim = 64;
  } else {
    int r = c - 4608; lane = r & 63; kf = 0; q = r>>6; W = w1ih; Kdim = DIN;
  }
  int ht = q/3, g3 = q - ht*3;
  int row = g3*64 + ht*16 + (lane & 15);
  int k = kf*32 + (lane>>4)*8 + e;
  float v = (k < Kdim) ? W[row*Kdim + k] : 0.f;
  wf[c*8 + e] = (_Float16)v;
}

// ---------------- fused 2-layer GRU + temporal attention (MFMA) ----------------
// grid 500 x 512. wave w: ht=w>>1 (hidden tile), nh=w&1 (seq tile of 16).
// Per step: out[192 x 32seq] = W @ h ; A=W frags in VGPR (f16 hi only),
// B=h frags from swizzled LDS (f16 hi+lo), C=f32 accum init'd with biases.
__global__ __launch_bounds__(512, 2) void gru_mfma(
    const float* __restrict__ raw,
    const _Float16* __restrict__ wf,
    const float* __restrict__ bih1, const float* __restrict__ bhh1,
    const float* __restrict__ bih2, const float* __restrict__ bhh2,
    const float* __restrict__ attnW, const float* __restrict__ attnb,
    float* __restrict__ Ai)
{
  __shared__ float xb[TT*32*16];                       // 64 KB, [t][seq][16] k-padded
  __shared__ _Float16 h1hi[32*64], h1lo[32*64];        // 8 KB
  __shared__ _Float16 h2hi[2][32*64], h2lo[2][32*64];  // 16 KB double-buffered
  __shared__ float attp[4][32];

  const int tid  = threadIdx.x;
  const int lane = tid & 63;
  const int wv   = tid >> 6;
  const int ht   = wv >> 1, nh = wv & 1;
  const int g    = lane >> 4;
  const int sl   = lane & 15;
  const int seq  = nh*16 + sl;            // local seq 0..31
  const int seq0 = blockIdx.x*32;

  // ---- prologue: zero pads/buffers, stage x ----
  for (int i = tid; i < TT*32*16; i += 512) xb[i] = 0.f;
  { int* z1 = (int*)h2hi; for (int i = tid; i < 2048; i += 512) z1[i] = 0;
    int* z2 = (int*)h2lo; for (int i = tid; i < 2048; i += 512) z2[i] = 0; }
  for (int i = tid; i < 32*TT*DIN; i += 512){
    int s = i / (TT*DIN); int rem = i - s*(TT*DIN);
    int t = rem / DIN;    int k  = rem - t*DIN;
    xb[t*512 + s*16 + k] = raw[(size_t)(seq0+s)*(TT*DIN) + rem];
  }

  // ---- weight fragments into VGPRs ----
  const f16x8* wf8 = (const f16x8*)wf;
  f16x8 wr1[2], wz1[2], wn1[2], xr1, xz1, xn1;
  f16x8 ar2[2], az2[2], an2[2], br2[2], bz2[2], bn2[2];
  #pragma unroll
  for (int kf=0;kf<2;++kf){
    wr1[kf] = wf8[        ((ht*3+0)*2+kf)*64 + lane];
    wz1[kf] = wf8[        ((ht*3+1)*2+kf)*64 + lane];
    wn1[kf] = wf8[        ((ht*3+2)*2+kf)*64 + lane];
    ar2[kf] = wf8[1536 +  ((ht*3+0)*2+kf)*64 + lane];
    az2[kf] = wf8[1536 +  ((ht*3+1)*2+kf)*64 + lane];
    an2[kf] = wf8[1536 +  ((ht*3+2)*2+kf)*64 + lane];
    br2[kf] = wf8[3072 +  ((ht*3+0)*2+kf)*64 + lane];
    bz2[kf] = wf8[3072 +  ((ht*3+1)*2+kf)*64 + lane];
    bn2[kf] = wf8[3072 +  ((ht*3+2)*2+kf)*64 + lane];
  }
  xr1 = wf8[4608 + (ht*3+0)*64 + lane];
  xz1 = wf8[4608 + (ht*3+1)*64 + lane];
  xn1 = wf8[4608 + (ht*3+2)*64 + lane];

  // ---- per-lane biases (C row = ht*16 + g*4 + r) ----
  const int row0 = ht*16 + g*4;
  f32x4 Br1, Bz1, Bxn1, Bhn1, Br2, Bz2, Bxn2, Bhn2, awv;
  #pragma unroll
  for (int r=0;r<4;++r){
    Br1[r]  = bih1[row0+r]     + bhh1[row0+r];
    Bz1[r]  = bih1[64+row0+r]  + bhh1[64+row0+r];
    Bxn1[r] = bih1[128+row0+r];
    Bhn1[r] = bhh1[128+row0+r];
    Br2[r]  = bih2[row0+r]     + bhh2[row0+r];
    Bz2[r]  = bih2[64+row0+r]  + bhh2[64+row0+r];
    Bxn2[r] = bih2[128+row0+r];
    Bhn2[r] = bhh2[128+row0+r];
    awv[r]  = attnW[row0+r];
  }
  const float ab = attnb[0];

  __syncthreads();

  const f16x8 fz = f16x8_zero();
  f16x8 h1f_hi[2] = {fz,fz}, h1f_lo[2] = {fz,fz};
  f32x4 h1c = {0.f,0.f,0.f,0.f}, h2c = {0.f,0.f,0.f,0.f}, num = {0.f,0.f,0.f,0.f};
  float den = 0.f;
  const int s7 = seq & 7;

  #pragma unroll 2
  for (int t=0; t<TT; ++t){
    // ---- x B-fragment (K rows 0..15 real, 16..31 zero pad) ----
    f16x8 xhi = fz, xlo = fz;
    if (lane < 32){
      const float* xp = &xb[t*512 + seq*16 + g*8];
      float4 a = *(const float4*)xp; float4 b = *(const float4*)(xp+4);
      float xv[8] = {a.x,a.y,a.z,a.w,b.x,b.y,b.z,b.w};
      #pragma unroll
      for (int j=0;j<8;++j){
        _Float16 h = (_Float16)xv[j];
        xhi[j] = h; xlo[j] = (_Float16)(xv[j] - (float)h);
      }
    }
    // ---- h2_old B-fragments from buffer (t+1)&1 ----
    f16x8 h2f_hi[2], h2f_lo[2];
    { const _Float16* bh = h2hi[(t+1)&1]; const _Float16* bl = h2lo[(t+1)&1];
      #pragma unroll
      for (int kf=0;kf<2;++kf){
        int c = (kf*4+g) ^ s7;
        h2f_hi[kf] = *(const f16x8*)(bh + seq*64 + c*8);
        h2f_lo[kf] = *(const f16x8*)(bl + seq*64 + c*8);
      } }
    // ---- temporal attention: finish step t-1 ----
    if (t > 0){
      float s4 = attp[0][seq]+attp[1][seq]+attp[2][seq]+attp[3][seq];
      float e = __expf(tanh_(s4 + ab));
      den += e;
      #pragma unroll
      for (int r=0;r<4;++r) num[r] = fmaf(e, h2c[r], num[r]);
    }
    // ---- layer1: 18 MFMAs ----
    f32x4 Cr = Br1, Cz = Bz1, Cxn = Bxn1, Chn = Bhn1;
    #pragma unroll
    for (int kf=0;kf<2;++kf){
      Cr  = MFMA(wr1[kf], h1f_hi[kf], Cr);  Cr  = MFMA(wr1[kf], h1f_lo[kf], Cr);
      Cz  = MFMA(wz1[kf], h1f_hi[kf], Cz);  Cz  = MFMA(wz1[kf], h1f_lo[kf], Cz);
      Chn = MFMA(wn1[kf], h1f_hi[kf], Chn); Chn = MFMA(wn1[kf], h1f_lo[kf], Chn);
    }
    Cr  = MFMA(xr1, xhi, Cr);  Cr  = MFMA(xr1, xlo, Cr);
    Cz  = MFMA(xz1, xhi, Cz);  Cz  = MFMA(xz1, xlo, Cz);
    Cxn = MFMA(xn1, xhi, Cxn); Cxn = MFMA(xn1, xlo, Cxn);
    // ---- gates layer1 -> h1_new, write swizzled f16 hi/lo ----
    f16x4 w_hi, w_lo;
    #pragma unroll
    for (int r=0;r<4;++r){
      float rg = sigm(Cr[r]);
      float zg = sigm(Cz[r]);
      float ng = tanh_(Cxn[r] + rg*Chn[r]);
      float h  = (1.f-zg)*ng + zg*h1c[r];
      h1c[r] = h;
      _Float16 hh = (_Float16)h;
      w_hi[r] = hh; w_lo[r] = (_Float16)(h - (float)hh);
    }
    { int cw = (ht*2 + (g>>1)) ^ s7;
      *(f16x4*)(h1hi + seq*64 + cw*8 + (g&1)*4) = w_hi;
      *(f16x4*)(h1lo + seq*64 + cw*8 + (g&1)*4) = w_lo; }
    __syncthreads();   // A: h1_new visible
    // ---- read h1_new B-fragments (also become h1_old for t+1) ----
    #pragma unroll
    for (int kf=0;kf<2;++kf){
      int c = (kf*4+g) ^ s7;
      h1f_hi[kf] = *(const f16x8*)(h1hi + seq*64 + c*8);
      h1f_lo[kf] = *(const f16x8*)(h1lo + seq*64 + c*8);
    }
    // ---- layer2: 24 MFMAs ----
    f32x4 Dr = Br2, Dz = Bz2, Dxn = Bxn2, Dhn = Bhn2;
    #pragma unroll
    for (int kf=0;kf<2;++kf){
      Dr  = MFMA(ar2[kf], h1f_hi[kf], Dr);  Dr  = MFMA(ar2[kf], h1f_lo[kf], Dr);
      Dr  = MFMA(br2[kf], h2f_hi[kf], Dr);  Dr  = MFMA(br2[kf], h2f_lo[kf], Dr);
      Dz  = MFMA(az2[kf], h1f_hi[kf], Dz);  Dz  = MFMA(az2[kf], h1f_lo[kf], Dz);
      Dz  = MFMA(bz2[kf], h2f_hi[kf], Dz);  Dz  = MFMA(bz2[kf], h2f_lo[kf], Dz);
      Dxn = MFMA(an2[kf], h1f_hi[kf], Dxn); Dxn = MFMA(an2[kf], h1f_lo[kf], Dxn);
      Dhn = MFMA(bn2[kf], h2f_hi[kf], Dhn); Dhn = MFMA(bn2[kf], h2f_lo[kf], Dhn);
    }
    // ---- gates layer2 -> h2_new, attention partial ----
    float p_att = 0.f;
    #pragma unroll
    for (int r=0;r<4;++r){
      float rg = sigm(Dr[r]);
      float zg = sigm(Dz[r]);
      float ng = tanh_(Dxn[r] + rg*Dhn[r]);
      float h  = (1.f-zg)*ng + zg*h2c[r];
      h2c[r] = h;
      p_att = fmaf(h, awv[r], p_att);
      _Float16 hh = (_Float16)h;
      w_hi[r] = hh; w_lo[r] = (_Float16)(h - (float)hh);
    }
    { _Float16* bh = h2hi[t&1]; _Float16* bl = h2lo[t&1];
      int cw = (ht*2 + (g>>1)) ^ s7;
      *(f16x4*)(bh + seq*64 + cw*8 + (g&1)*4) = w_hi;
      *(f16x4*)(bl + seq*64 + cw*8 + (g&1)*4) = w_lo; }
    p_att += __shfl_xor(p_att, 16, 64);
    p_att += __shfl_xor(p_att, 32, 64);
    if (g == 0) attp[ht][seq] = p_att;
    __syncthreads();   // B: h2_new + attp visible
  }
  // ---- finish attention for t=TT-1, write Ai ----
  {
    float s4 = attp[0][seq]+attp[1][seq]+attp[2][seq]+attp[3][seq];
    float e = __expf(tanh_(s4 + ab));
    den += e;
    #pragma unroll
    for (int r=0;r<4;++r) num[r] = fmaf(e, h2c[r], num[r]);
  }
  float4 o = make_float4(num[0]/den, num[1]/den, num[2]/den, num[3]/den);
  *(float4*)&Ai[(size_t)(seq0+seq)*64 + row0] = o;
}

// ---------------- GAT projections: sq -> (s_q,s_k), proj ----------------
__global__ __launch_bounds__(256) void gat_proj(
    const float* __restrict__ Ai,
    const float* __restrict__ Ww, const float* __restrict__ Wb,
    const float* __restrict__ u,
    const float* __restrict__ W1, const float* __restrict__ W1b,
    float* __restrict__ sqo, float* __restrict__ sko, float* __restrict__ proj)
{
  __shared__ float wws[64*64];
  __shared__ float w1s[64*64];
  __shared__ float rowb[4*64];
  const int tid = threadIdx.x;
  {
    const float4* s1=(const float4*)Ww; const float4* s2=(const float4*)W1;
    float4* d1=(float4*)wws; float4* d2=(float4*)w1s;
    #pragma unroll
    for (int f=0; f<4; ++f){
      const int i4 = tid + f*256;
      const int j = i4 >> 4, c = i4 & 15;
      const int dst = j*16 + (c ^ (j & 15));
      d1[dst]=s1[i4]; d2[dst]=s2[i4];
    }
  }
  const int lane = tid & 63;
  const int wave = tid >> 6;
  const int row = blockIdx.x*4 + wave;
  const float ai = Ai[(size_t)row*64 + lane];
  rowb[wave*64+lane] = ai;
  __syncthreads();

  float sq = Wb[lane], pj = W1b[lane];
  #pragma unroll 4
  for (int c=0;c<16;++c){
    const int cs = c ^ (lane & 15);
    const float4 a4 = ((const float4*)rowb)[wave*16 + c];
    const float4 w4 = ((const float4*)wws)[lane*16 + cs];
    const float4 v4 = ((const float4*)w1s)[lane*16 + cs];
    sq = dot4(a4,w4,sq); pj = dot4(a4,v4,pj);
  }
  float aq = sq*u[lane];
  float ak = sq*u[64+lane];
  #pragma unroll
  for (int off=32; off>0; off>>=1){ aq += __shfl_xor(aq,off,64); ak += __shfl_xor(ak,off,64); }
  if (lane==0){ sqo[row]=aq; sko[row]=ak; }
  proj[(size_t)row*64+lane] = pj;
}

// ---------------- GAT aggregation ----------------
__global__ __launch_bounds__(256) void gat_agg(
    const float* __restrict__ sqo, const float* __restrict__ sko,
    const float* __restrict__ proj, float* __restrict__ out)
{
  const int tid = threadIdx.x;
  const int lane = tid & 63;
  const int w = blockIdx.x*4 + (tid>>6);
  const int b = w & 31;
  const int q0 = (w >> 5) * 4;
  float sq[4], den[4]={0,0,0,0}, acc[4]={0,0,0,0};
  #pragma unroll
  for (int i=0;i<4;++i) sq[i] = sqo[(q0+i)*32 + b];
  for (int k=0;k<500;++k){
    const float sk = sko[k*32 + b];
    const float p  = proj[(size_t)(k*32 + b)*64 + lane];
    #pragma unroll
    for (int i=0;i<4;++i){
      float sc = sq[i] + sk;
      sc = sc > 0.f ? sc : 0.01f*sc;
      const float e = __expf(sc);
      den[i] += e; acc[i] = fmaf(e, p, acc[i]);
    }
  }
  #pragma unroll
  for (int i=0;i<4;++i){
    const float g = acc[i]/den[i];
    out[(size_t)((q0+i)*32 + b)*64 + lane] = g > 0.f ? g : 0.f;
  }
}

extern "C" void kernel_launch(void* const* d_in, const int* in_sizes, int n_in,
                              void* d_out, int out_size, void* d_ws, size_t ws_size,
                              hipStream_t stream) {
  const float* raw   = (const float*)d_in[0];
  const float* w1ih  = (const float*)d_in[1];
  const float* w1hh  = (const float*)d_in[2];
  const float* b1ih  = (const float*)d_in[3];
  const float* b1hh  = (const float*)d_in[4];
  const float* w2ih  = (const float*)d_in[5];
  const float* w2hh  = (const float*)d_in[6];
  const float* b2ih  = (const float*)d_in[7];
  const float* b2hh  = (const float*)d_in[8];
  const float* attW  = (const float*)d_in[9];
  const float* attb  = (const float*)d_in[10];
  const float* gWw   = (const float*)d_in[11];
  const float* gWb   = (const float*)d_in[12];
  const float* gu    = (const float*)d_in[13];
  const float* gW1   = (const float*)d_in[14];
  const float* gW1b  = (const float*)d_in[15];
  float* outp = (float*)d_out;

  float* ws   = (float*)d_ws;
  float* Ai   = ws;                       // 1,024,000 f32
  float* proj = ws + 1024000;             // 1,024,000 f32 (reused after gru: overlaps wf)
  float* sqo  = ws + 2048000;             // 16,000
  float* sko  = ws + 2064000;             // 16,000
  _Float16* wfh = (_Float16*)(ws + 1024000);  // 43,008 f16 — dead before gat_proj writes proj

  wprep<<<168, 256, 0, stream>>>(w1ih, w1hh, w2ih, w2hh, wfh);
  gru_mfma<<<500, 512, 0, stream>>>(raw, wfh, b1ih, b1hh, b2ih, b2hh, attW, attb, Ai);
  gat_proj<<<4000, 256, 0, stream>>>(Ai, gWw, gWb, gu, gW1, gW1b, sqo, sko, proj);
  gat_agg<<<1000, 256, 0, stream>>>(sqo, sko, proj, outp);
}

// Round 3
// 200.776 us; speedup vs baseline: 4.5666x; 1.5470x over previous
//
#include <hip/hip_runtime.h>

#define TT 32
#define DIN 15
#define LOG2E 1.44269504088896340736f

typedef _Float16 f16x8 __attribute__((ext_vector_type(8)));
typedef _Float16 f16x4 __attribute__((ext_vector_type(4)));
typedef float f32x4 __attribute__((ext_vector_type(4)));

__device__ __forceinline__ float rcp_(float x){ return __builtin_amdgcn_rcpf(x); }
__device__ __forceinline__ float sigm(float x){ return rcp_(1.f+__expf(-x)); }
// safe tanh via rcp (never NaN on overflow)
__device__ __forceinline__ float tanh_(float x){ return fmaf(-2.f, rcp_(__expf(2.f*x)+1.f), 1.f); }
__device__ __forceinline__ float dot4(float4 a, float4 b, float acc){
  acc = fmaf(a.x,b.x,acc); acc = fmaf(a.y,b.y,acc);
  acc = fmaf(a.z,b.z,acc); acc = fmaf(a.w,b.w,acc); return acc;
}

#define MFMA(a,b,c) __builtin_amdgcn_mfma_f32_16x16x32_f16(a,b,c,0,0,0)

__device__ __forceinline__ f16x8 f16x8_zero(){
  f16x8 v;
  #pragma unroll
  for (int j=0;j<8;++j) v[j]=(_Float16)0.f;
  return v;
}

// ---------------- prep: W -> f16 A-fragments ----------------
// chunk layout (16B units): whh1 @0, wih2 @1536, whh2 @3072: idx=((ht*3+g3)*2+kf)*64+lane
//   wih1 @4608 (kf=0, K padded 15->32): idx=(ht*3+g3)*64+lane
// element e: W[g3*64 + ht*16 + (lane&15)][kf*32 + (lane>>4)*8 + e]
// wih1 k=15 column carries the folded biases (x k15 channel is constant 1.0):
//   g3<2: bih1[row]+bhh1[row]; g3==2: bih1[row]
__global__ void wprep(const float* __restrict__ w1ih, const float* __restrict__ w1hh,
                      const float* __restrict__ w2ih, const float* __restrict__ w2hh,
                      const float* __restrict__ b1ih, const float* __restrict__ b1hh,
                      _Float16* __restrict__ wf){
  int id = blockIdx.x*256 + threadIdx.x;   // 0..43007
  if (id >= 43008) return;
  int e = id & 7, c = id >> 3;             // c: 0..5375
  float v;
  if (c < 4608){
    int mat = c / 1536; int r = c - mat*1536;
    int lane = r & 63, kf = (r>>6)&1, q = r>>7;
    const float* W = (mat==0)? w1hh : (mat==1)? w2ih : w2hh;
    int ht = q/3, g3 = q - ht*3;
    int row = g3*64 + ht*16 + (lane & 15);
    int k = kf*32 + (lane>>4)*8 + e;
    v = W[row*64 + k];
  } else {
    int r = c - 4608; int lane = r & 63, q = r>>6;
    int ht = q/3, g3 = q - ht*3;
    int row = g3*64 + ht*16 + (lane & 15);
    int k = (lane>>4)*8 + e;
    if (k < DIN)       v = w1ih[row*DIN + k];
    else if (k == DIN) v = (g3 < 2) ? (b1ih[row] + b1hh[row]) : b1ih[row];
    else               v = 0.f;
  }
  wf[c*8 + e] = (_Float16)v;
}

// ---------------- fused 2-layer GRU + temporal attention (MFMA, f16-hi) ----------------
// grid 1000 x 256 (4 waves). Block owns 16 sequences; wave = hidden tile ht.
__global__ __launch_bounds__(256, 3) void gru_mfma(
    const float* __restrict__ raw,
    const _Float16* __restrict__ wf,
    const float* __restrict__ bhh1,
    const float* __restrict__ bih2, const float* __restrict__ bhh2,
    const float* __restrict__ attnW, const float* __restrict__ attnb,
    float* __restrict__ Ai)
{
  __shared__ _Float16 xfh[TT*32*8];   // 16KB: x B-frag chunks, (t*32 + g*16 + s)*8
  __shared__ _Float16 h1s[16*64];     // 2KB, XOR-swizzled chunks
  __shared__ _Float16 h2s[16*64];     // 2KB
  __shared__ float bias2[256];        // l2 gate-init biases
  __shared__ float attp[4][16];

  const int tid  = threadIdx.x;
  const int lane = tid & 63;
  const int ht   = tid >> 6;
  const int g    = lane >> 4;
  const int sl   = lane & 15;
  const int s7   = sl & 7;
  const int seq0 = blockIdx.x*16;
  const int row0 = ht*16 + g*4;

  // ---- prologue ----
  { int* z1 = (int*)h1s; int* z2 = (int*)h2s;
    for (int i=tid; i<512; i+=256){ z1[i]=0; z2[i]=0; } }
  if (tid < 64){
    bias2[tid]       = bih2[tid]      + bhh2[tid];
    bias2[64+tid]    = bih2[64+tid]   + bhh2[64+tid];
    bias2[128+tid]   = bih2[128+tid];
    bias2[192+tid]   = bhh2[128+tid];
  }
  for (int idx=tid; idx<16*TT*16; idx+=256){
    int k16 = idx & 15, t = (idx>>4)&31, s = idx>>9;
    float v = (k16 < DIN) ? raw[(size_t)(seq0+s)*(TT*DIN) + t*DIN + k16]
                          : (k16 == DIN ? 1.0f : 0.f);
    xfh[((size_t)t*32 + (k16>>3)*16 + s)*8 + (k16&7)] = (_Float16)v;
  }

  // ---- weight fragments (hi only, 84 VGPR) ----
  const f16x8* wf8 = (const f16x8*)wf;
  f16x8 wr1_0 = wf8[((ht*3+0)*2+0)*64 + lane], wr1_1 = wf8[((ht*3+0)*2+1)*64 + lane];
  f16x8 wz1_0 = wf8[((ht*3+1)*2+0)*64 + lane], wz1_1 = wf8[((ht*3+1)*2+1)*64 + lane];
  f16x8 wn1_0 = wf8[((ht*3+2)*2+0)*64 + lane], wn1_1 = wf8[((ht*3+2)*2+1)*64 + lane];
  f16x8 ar2_0 = wf8[1536+((ht*3+0)*2+0)*64 + lane], ar2_1 = wf8[1536+((ht*3+0)*2+1)*64 + lane];
  f16x8 az2_0 = wf8[1536+((ht*3+1)*2+0)*64 + lane], az2_1 = wf8[1536+((ht*3+1)*2+1)*64 + lane];
  f16x8 an2_0 = wf8[1536+((ht*3+2)*2+0)*64 + lane], an2_1 = wf8[1536+((ht*3+2)*2+1)*64 + lane];
  f16x8 br2_0 = wf8[3072+((ht*3+0)*2+0)*64 + lane], br2_1 = wf8[3072+((ht*3+0)*2+1)*64 + lane];
  f16x8 bz2_0 = wf8[3072+((ht*3+1)*2+0)*64 + lane], bz2_1 = wf8[3072+((ht*3+1)*2+1)*64 + lane];
  f16x8 bn2_0 = wf8[3072+((ht*3+2)*2+0)*64 + lane], bn2_1 = wf8[3072+((ht*3+2)*2+1)*64 + lane];
  f16x8 xr1 = wf8[4608 + (ht*3+0)*64 + lane];
  f16x8 xz1 = wf8[4608 + (ht*3+1)*64 + lane];
  f16x8 xn1 = wf8[4608 + (ht*3+2)*64 + lane];

  f32x4 Bhn1, awv;
  #pragma unroll
  for (int r=0;r<4;++r){ Bhn1[r] = bhh1[128+row0+r]; awv[r] = attnW[row0+r]; }
  const float ab = attnb[0];

  __syncthreads();

  const f16x8 fz = f16x8_zero();
  f16x8 h1f0 = fz, h1f1 = fz;
  f32x4 h1c = {0,0,0,0}, h2c = {0,0,0,0}, num = {0,0,0,0};
  float den = 0.f;

  #pragma unroll 1
  for (int t=0; t<TT; ++t){
    // ---- fresh B-fragments (pre-barrier-A reads) ----
    f16x8 xf = fz;
    if (lane < 32) xf = *(const f16x8*)(xfh + ((size_t)t*32 + lane)*8);
    f16x8 h2f0 = *(const f16x8*)(h2s + sl*64 + ((g    ^ s7))*8);
    f16x8 h2f1 = *(const f16x8*)(h2s + sl*64 + (((4+g)^ s7))*8);
    if (t > 0){
      float s4 = attp[0][sl]+attp[1][sl]+attp[2][sl]+attp[3][sl];
      float e = __expf(tanh_(s4 + ab));
      den += e;
      #pragma unroll
      for (int r=0;r<4;++r) num[r] = fmaf(e, h2c[r], num[r]);
    }
    // ---- layer1: 9 MFMAs (biases folded into x k15 channel) ----
    f32x4 Cr = {0,0,0,0}, Cz = {0,0,0,0}, Cxn = {0,0,0,0}, Chn = Bhn1;
    Cr  = MFMA(wr1_0, h1f0, Cr);  Cr  = MFMA(wr1_1, h1f1, Cr);  Cr  = MFMA(xr1, xf, Cr);
    Cz  = MFMA(wz1_0, h1f0, Cz);  Cz  = MFMA(wz1_1, h1f1, Cz);  Cz  = MFMA(xz1, xf, Cz);
    Chn = MFMA(wn1_0, h1f0, Chn); Chn = MFMA(wn1_1, h1f1, Chn);
    Cxn = MFMA(xn1, xf, Cxn);
    // ---- gates l1 -> h1_new (f16) ----
    f16x4 hw;
    #pragma unroll
    for (int r=0;r<4;++r){
      float rg = sigm(Cr[r]);
      float zg = sigm(Cz[r]);
      float ng = tanh_(Cxn[r] + rg*Chn[r]);
      float h  = ng + zg*(h1c[r] - ng);
      h1c[r] = h; hw[r] = (_Float16)h;
    }
    *(f16x4*)(h1s + sl*64 + (((ht*2+(g>>1)) ^ s7))*8 + (g&1)*4) = hw;
    __syncthreads();   // A: h1_new visible; orders h2 reads before h2 writes
    h1f0 = *(const f16x8*)(h1s + sl*64 + ((g    ^ s7))*8);
    h1f1 = *(const f16x8*)(h1s + sl*64 + (((4+g)^ s7))*8);
    // ---- layer2: 12 MFMAs, biases from LDS broadcast ----
    f32x4 Dr  = *(const f32x4*)(bias2 + row0);
    f32x4 Dz  = *(const f32x4*)(bias2 + 64 + row0);
    f32x4 Dxn = *(const f32x4*)(bias2 + 128 + row0);
    f32x4 Dhn = *(const f32x4*)(bias2 + 192 + row0);
    Dr  = MFMA(ar2_0, h1f0, Dr);  Dr  = MFMA(ar2_1, h1f1, Dr);
    Dr  = MFMA(br2_0, h2f0, Dr);  Dr  = MFMA(br2_1, h2f1, Dr);
    Dz  = MFMA(az2_0, h1f0, Dz);  Dz  = MFMA(az2_1, h1f1, Dz);
    Dz  = MFMA(bz2_0, h2f0, Dz);  Dz  = MFMA(bz2_1, h2f1, Dz);
    Dxn = MFMA(an2_0, h1f0, Dxn); Dxn = MFMA(an2_1, h1f1, Dxn);
    Dhn = MFMA(bn2_0, h2f0, Dhn); Dhn = MFMA(bn2_1, h2f1, Dhn);
    // ---- gates l2 -> h2_new, attention partial ----
    float p_att = 0.f;
    #pragma unroll
    for (int r=0;r<4;++r){
      float rg = sigm(Dr[r]);
      float zg = sigm(Dz[r]);
      float ng = tanh_(Dxn[r] + rg*Dhn[r]);
      float h  = ng + zg*(h2c[r] - ng);
      h2c[r] = h; hw[r] = (_Float16)h;
      p_att = fmaf(h, awv[r], p_att);
    }
    *(f16x4*)(h2s + sl*64 + (((ht*2+(g>>1)) ^ s7))*8 + (g&1)*4) = hw;
    p_att += __shfl_xor(p_att, 16, 64);
    p_att += __shfl_xor(p_att, 32, 64);
    if (lane < 16) attp[ht][sl] = p_att;
    __syncthreads();   // B: h2_new + attp visible
  }
  // ---- finish attention (t=TT-1), write Ai ----
  {
    float s4 = attp[0][sl]+attp[1][sl]+attp[2][sl]+attp[3][sl];
    float e = __expf(tanh_(s4 + ab));
    den += e;
    #pragma unroll
    for (int r=0;r<4;++r) num[r] = fmaf(e, h2c[r], num[r]);
  }
  float rd = rcp_(den);
  float4 o = make_float4(num[0]*rd, num[1]*rd, num[2]*rd, num[3]*rd);
  *(float4*)&Ai[(size_t)(seq0+sl)*64 + row0] = o;
}

// ---------------- GAT projections: one node per block, weights staged once ----------------
__global__ __launch_bounds__(256) void gat_proj(
    const float* __restrict__ Ai,
    const float* __restrict__ Ww, const float* __restrict__ Wb,
    const float* __restrict__ u,
    const float* __restrict__ W1, const float* __restrict__ W1b,
    float* __restrict__ sqo, float* __restrict__ sko, float* __restrict__ proj)
{
  __shared__ float wws[64*64];
  __shared__ float w1s[64*64];
  __shared__ float rowb[32*64];
  const int tid = threadIdx.x;
  const int n = blockIdx.x;
  {
    const float4* s1=(const float4*)Ww; const float4* s2=(const float4*)W1;
    float4* d1=(float4*)wws; float4* d2=(float4*)w1s;
    #pragma unroll
    for (int f=0; f<4; ++f){
      const int i4 = tid + f*256;
      const int j = i4 >> 4, c = i4 & 15;
      const int dst = j*16 + (c ^ (j & 15));
      d1[dst]=s1[i4]; d2[dst]=s2[i4];
    }
  }
  for (int i=tid; i<2048; i+=256) rowb[i] = Ai[(size_t)n*2048 + i];
  __syncthreads();

  const int lane = tid & 63;
  const int wave = tid >> 6;
  const float u0 = u[lane], u1 = u[64+lane];
  const float wb = Wb[lane], w1b = W1b[lane];

  for (int b = wave; b < 32; b += 4){
    float sq = wb, pj = w1b;
    #pragma unroll 4
    for (int c=0;c<16;++c){
      const int cs = c ^ (lane & 15);
      const float4 a4 = ((const float4*)rowb)[b*16 + c];
      const float4 w4 = ((const float4*)wws)[lane*16 + cs];
      const float4 v4 = ((const float4*)w1s)[lane*16 + cs];
      sq = dot4(a4,w4,sq); pj = dot4(a4,v4,pj);
    }
    float aq = sq*u0;
    float ak = sq*u1;
    #pragma unroll
    for (int off=32; off>0; off>>=1){ aq += __shfl_xor(aq,off,64); ak += __shfl_xor(ak,off,64); }
    const int row = n*32 + b;
    if (lane==0){ sqo[row]=aq*LOG2E; sko[row]=ak*LOG2E; }   // pre-scaled for exp2
    proj[(size_t)row*64+lane] = pj;
  }
}

// ---------------- GAT aggregation (exp2 on pre-scaled scores) ----------------
__global__ __launch_bounds__(256) void gat_agg(
    const float* __restrict__ sqo, const float* __restrict__ sko,
    const float* __restrict__ proj, float* __restrict__ out)
{
  const int tid = threadIdx.x;
  const int lane = tid & 63;
  const int w = blockIdx.x*4 + (tid>>6);
  const int b = w & 31;
  const int q0 = (w >> 5) * 4;
  float sq[4], den[4]={0,0,0,0}, acc[4]={0,0,0,0};
  #pragma unroll
  for (int i=0;i<4;++i) sq[i] = sqo[(q0+i)*32 + b];
  for (int k=0;k<500;++k){
    const float sk = sko[k*32 + b];
    const float p  = proj[(size_t)(k*32 + b)*64 + lane];
    #pragma unroll
    for (int i=0;i<4;++i){
      float sc = sq[i] + sk;
      sc = fmaxf(sc, 0.01f*sc);                 // leaky_relu (scale-commuting)
      const float e = __builtin_amdgcn_exp2f(sc);
      den[i] += e; acc[i] = fmaf(e, p, acc[i]);
    }
  }
  #pragma unroll
  for (int i=0;i<4;++i){
    const float g = acc[i]*rcp_(den[i]);
    out[(size_t)((q0+i)*32 + b)*64 + lane] = g > 0.f ? g : 0.f;
  }
}

extern "C" void kernel_launch(void* const* d_in, const int* in_sizes, int n_in,
                              void* d_out, int out_size, void* d_ws, size_t ws_size,
                              hipStream_t stream) {
  const float* raw   = (const float*)d_in[0];
  const float* w1ih  = (const float*)d_in[1];
  const float* w1hh  = (const float*)d_in[2];
  const float* b1ih  = (const float*)d_in[3];
  const float* b1hh  = (const float*)d_in[4];
  const float* w2ih  = (const float*)d_in[5];
  const float* w2hh  = (const float*)d_in[6];
  const float* b2ih  = (const float*)d_in[7];
  const float* b2hh  = (const float*)d_in[8];
  const float* attW  = (const float*)d_in[9];
  const float* attb  = (const float*)d_in[10];
  const float* gWw   = (const float*)d_in[11];
  const float* gWb   = (const float*)d_in[12];
  const float* gu    = (const float*)d_in[13];
  const float* gW1   = (const float*)d_in[14];
  const float* gW1b  = (const float*)d_in[15];
  float* outp = (float*)d_out;

  float* ws   = (float*)d_ws;
  float* Ai   = ws;                        // 1,024,000 f32
  float* proj = ws + 1024000;              // 1,024,000 f32
  float* sqo  = ws + 2048000;              // 16,000
  float* sko  = ws + 2064000;              // 16,000
  _Float16* wfh = (_Float16*)(ws + 2080000);  // 43,008 f16

  wprep<<<168, 256, 0, stream>>>(w1ih, w1hh, w2ih, w2hh, b1ih, b1hh, wfh);
  gru_mfma<<<1000, 256, 0, stream>>>(raw, wfh, b1hh, b2ih, b2hh, attW, attb, Ai);
  gat_proj<<<500, 256, 0, stream>>>(Ai, gWw, gWb, gu, gW1, gW1b, sqo, sko, proj);
  gat_agg<<<1000, 256, 0, stream>>>(sqo, sko, proj, outp);
}